// Round 9
// baseline (13.505 us; speedup 1.0000x reference)
//
#include <hip/hip_runtime.h>
#include <math.h>

#define NB 128   // batch
#define NL 16    // num_site
#define NM 32    // M
#define NP 4     // P
#define NMP 128  // M*P

// Kernel 1: 2 blocks per batch element b (h = k-half), 1024 threads (16 waves).
// Thread owns ONE j-row in registers (j = t&127). Group g = t>>7 handles
// k in [h*64 + 8g, 8). g is wave-uniform -> cs[l][k] reads are LDS broadcasts;
// each group's 128 threads cover all 128 j (R6 lesson: full pair coverage).
// Block 0 additionally pre-reduces the three regularizers into ws reg_total
// (block-uniform branch; theta/coef are cache-warm; other blocks unaffected).
__global__ __launch_bounds__(1024) void per_b_kernel(
    const float* __restrict__ ds, const float* __restrict__ theta,
    const float* __restrict__ coef, float* __restrict__ wnorm,
    float* __restrict__ wamp, float* __restrict__ wreg)
{
    const int b    = blockIdx.x >> 1;
    const int h    = blockIdx.x & 1;
    const int t    = threadIdx.x;
    const int lane = t & 63;
    const int w    = t >> 6;      // wave id 0..15

    __shared__ float2 cs[NL][NMP];   // (cos, sin) of u[l][j]
    __shared__ float  co[NMP];
    __shared__ float  dsrow[NL];
    __shared__ float  redN[16], redA[16];
    __shared__ float  r4[4][16];

    if (t < NL)  dsrow[t] = ds[b * NL + t];
    if (t < NMP) co[t]    = coef[t];
    __syncthreads();

    // 2048 sincos, 2 per thread (fast intrinsic; |u| < 3, accuracy verified)
    #pragma unroll
    for (int i = t; i < NL * NMP; i += 1024) {
        int l = i >> 7;
        int j = i & (NMP - 1);
        int p = j & 3;
        float sf = (float)M_PI / (float)(2 << p);   // pi / 2^(p+1)
        float u  = theta[i] + sf * dsrow[l];
        float ss, cc;
        __sincosf(u, &ss, &cc);
        cs[l][j] = make_float2(cc, ss);
    }
    __syncthreads();

    // j-row into registers (32 VGPRs); conflict-free (lanes stride 8B)
    const int j = t & (NMP - 1);
    float rc[NL], rs[NL];
    #pragma unroll
    for (int l = 0; l < NL; ++l) { float2 v = cs[l][j]; rc[l] = v.x; rs[l] = v.y; }
    const float wj = co[j];

    // amp partial: waves 0,1 (t<128) cover j = 0..127 exactly once
    float amp_part = 0.f;
    if (w < 2) {
        float p0 = wj;
        #pragma unroll
        for (int l = 0; l < NL; ++l) p0 *= rc[l];
        amp_part = p0;
    }

    // group g handles 8 k; cs[l][k] wave-uniform -> LDS broadcast
    float norm_part = 0.f;
    const int k0 = h * 64 + (t >> 7) * 8;
    #pragma unroll 4
    for (int ki = 0; ki < 8; ++ki) {
        int k = k0 + ki;
        float pp = 1.f;
        #pragma unroll
        for (int l = 0; l < NL; ++l) {
            float2 v = cs[l][k];
            pp *= fmaf(rc[l], v.x, rs[l] * v.y);   // cos(u_j - u_k)
        }
        norm_part = fmaf(wj * pp, co[k], norm_part);
    }

    // wave64 butterfly + cross-wave reduce
    #pragma unroll
    for (int off = 32; off > 0; off >>= 1) {
        norm_part += __shfl_xor(norm_part, off);
        amp_part  += __shfl_xor(amp_part,  off);
    }
    if (lane == 0) { redN[w] = norm_part; redA[w] = amp_part; }
    __syncthreads();
    if (t == 0) {
        float n = 0.f, a = 0.f;
        #pragma unroll
        for (int i = 0; i < 16; ++i) { n += redN[i]; a += redA[i]; }
        wnorm[b * 2 + h] = n;
        if (h == 0) wamp[b] = a;
    }

    // ---- regularizers: block 0 only (block-uniform branch) ----
    if (blockIdx.x == 0) {
        float cv = (t < NMP) ? co[t] : 0.f;
        float v2 = cv, v3 = cv * cv, v4 = 0.f, v5 = 0.f;
        if (t < NL * NP) {   // reg_theta_m: var over M per (l,p), ddof=1
            int l = t >> 2, p = t & 3;
            float sum = 0.f, sum2 = 0.f;
            for (int m = 0; m < NM; ++m) {
                float x = theta[(l * NM + m) * NP + p];
                sum += x; sum2 += x * x;
            }
            v4 = (sum2 - sum * sum / (float)NM) / (float)(NM - 1);
        }
        if (t < NL * NM) {   // reg_theta_p: one float4 per (l,m), var over P=4
            float4 th = reinterpret_cast<const float4*>(theta)[t];
            float sum  = th.x + th.y + th.z + th.w;
            float sum2 = th.x * th.x + th.y * th.y + th.z * th.z + th.w * th.w;
            v5 = (sum2 - sum * sum * 0.25f) * (1.f / 3.f);
        }
        #pragma unroll
        for (int off = 32; off > 0; off >>= 1) {
            v2 += __shfl_xor(v2, off);
            v3 += __shfl_xor(v3, off);
            v4 += __shfl_xor(v4, off);
            v5 += __shfl_xor(v5, off);
        }
        if (lane == 0) { r4[0][w] = v2; r4[1][w] = v3; r4[2][w] = v4; r4[3][w] = v5; }
        __syncthreads();
        if (t == 0) {
            float s2 = 0.f, s3 = 0.f, s4 = 0.f, s5 = 0.f;
            #pragma unroll
            for (int i = 0; i < 16; ++i) {
                s2 += r4[0][i]; s3 += r4[1][i]; s4 += r4[2][i]; s5 += r4[3][i];
            }
            float reg_c  = (s3 - s2 * s2 / (float)NMP) / (float)(NMP - 1);
            float reg_tm = s4 / (float)(NL * NP);
            float reg_tp = s5 / (float)(NL * NM);
            wreg[0] = 0.01f * (reg_c + reg_tm + reg_tp);
        }
    }
}

// Kernel 2: ONE wave (64 threads), zero barriers. Each lane handles 2 batch
// elements; butterfly-reduce; lane 0 adds pre-reduced reg_total and stores.
__global__ __launch_bounds__(64) void finalize_kernel(
    const float* __restrict__ wnorm, const float* __restrict__ wamp,
    const float* __restrict__ wreg, float* __restrict__ out)
{
    const int t = threadIdx.x;

    float a0 = wamp[t];
    float a1 = wamp[t + 64];
    float2 n0 = reinterpret_cast<const float2*>(wnorm)[t];
    float2 n1 = reinterpret_cast<const float2*>(wnorm)[t + 64];
    float mnl = -__logf(a0 * a0 / (n0.x + n0.y) + 1e-20f)
                -__logf(a1 * a1 / (n1.x + n1.y) + 1e-20f);

    #pragma unroll
    for (int off = 32; off > 0; off >>= 1)
        mnl += __shfl_xor(mnl, off);

    if (t == 0)
        out[0] = mnl * (1.f / (float)NB) + wreg[0];
}

extern "C" void kernel_launch(void* const* d_in, const int* in_sizes, int n_in,
                              void* d_out, int out_size, void* d_ws, size_t ws_size,
                              hipStream_t stream) {
    const float* ds    = (const float*)d_in[0];  // (B, L)
    const float* theta = (const float*)d_in[1];  // (L, M, P)
    const float* coef  = (const float*)d_in[2];  // (M, P)
    float* wnorm = (float*)d_ws;                 // 256 floats
    float* wamp  = (float*)d_ws + 2 * NB;        // 128 floats
    float* wreg  = (float*)d_ws + 3 * NB;        // 1 float
    float* out   = (float*)d_out;

    per_b_kernel<<<2 * NB, 1024, 0, stream>>>(ds, theta, coef, wnorm, wamp, wreg);
    finalize_kernel<<<1, 64, 0, stream>>>(wnorm, wamp, wreg, out);
}

// Round 10
// 12.832 us; speedup vs baseline: 1.0524x; 1.0524x over previous
//
#include <hip/hip_runtime.h>
#include <math.h>

#define NB 128   // batch
#define NL 16    // num_site
#define NM 32    // M
#define NP 4     // P
#define NMP 128  // M*P

// FINAL CONFIG (= R4, best measured: 12.79 us).
// Kernel 1: 2 blocks per batch element b (h = k-half). 512 threads.
// Thread owns TWO j-rows in registers (j = lane, lane+64); wave w owns a
// k-chunk of 8. Each cs[l][k] LDS read is wave-uniform (broadcast) and
// feeds 2 pairs. cos(u_j - u_k) = cos_j*cos_k + sin_j*sin_k.
// Lessons encoded: 2-kernel split beats fence/last-block fusion (+9.6us),
// memset-node fusion (+5.5us); grid 256 beats 512 (prologue duplication);
// symmetric per-block work only (block-0 tails extend the dispatch).
__global__ __launch_bounds__(512) void per_b_kernel(
    const float* __restrict__ ds, const float* __restrict__ theta,
    const float* __restrict__ coef, float* __restrict__ wnorm,
    float* __restrict__ wamp)
{
    const int b    = blockIdx.x >> 1;
    const int h    = blockIdx.x & 1;
    const int t    = threadIdx.x;
    const int lane = t & 63;
    const int w    = t >> 6;      // wave id 0..7

    __shared__ float2 cs[NL][NMP];   // (cos, sin) of u[l][j]
    __shared__ float  co[NMP];
    __shared__ float  dsrow[NL];
    __shared__ float  redN[8], redA[8];

    if (t < NL)  dsrow[t] = ds[b * NL + t];
    if (t < NMP) co[t]    = coef[t];
    __syncthreads();

    // 2048 sincos, 4 per thread (fast intrinsic; |u| < 3, accuracy verified)
    for (int i = t; i < NL * NMP; i += 512) {
        int l = i >> 7;
        int j = i & (NMP - 1);
        int p = j & 3;
        float sf = (float)M_PI / (float)(2 << p);   // pi / 2^(p+1)
        float u  = theta[i] + sf * dsrow[l];
        float ss, cc;
        __sincosf(u, &ss, &cc);
        cs[l][j] = make_float2(cc, ss);
    }
    __syncthreads();

    // two j-rows into registers (64 VGPRs)
    float rc0[NL], rs0[NL], rc1[NL], rs1[NL];
    #pragma unroll
    for (int l = 0; l < NL; ++l) {
        float2 v0 = cs[l][lane];      rc0[l] = v0.x; rs0[l] = v0.y;
        float2 v1 = cs[l][lane + 64]; rc1[l] = v1.x; rs1[l] = v1.y;
    }
    const float wj0 = co[lane], wj1 = co[lane + 64];

    // amp partial: wave 0 only
    float amp_part = 0.f;
    if (w == 0) {
        float p0 = wj0, p1 = wj1;
        #pragma unroll
        for (int l = 0; l < NL; ++l) { p0 *= rc0[l]; p1 *= rc1[l]; }
        amp_part = p0 + p1;
    }

    // 8 k per wave; cs[l][k] wave-uniform -> LDS broadcast, feeds both rows
    float norm_part = 0.f;
    const int k0 = h * 64 + w * 8;
    #pragma unroll 4
    for (int ki = 0; ki < 8; ++ki) {
        int k = k0 + ki;
        float pp0 = 1.f, pp1 = 1.f;
        #pragma unroll
        for (int l = 0; l < NL; ++l) {
            float2 v = cs[l][k];
            pp0 *= fmaf(rc0[l], v.x, rs0[l] * v.y);
            pp1 *= fmaf(rc1[l], v.x, rs1[l] * v.y);
        }
        norm_part = fmaf(fmaf(wj1, pp1, wj0 * pp0), co[k], norm_part);
    }

    // wave64 butterfly + cross-wave reduce
    #pragma unroll
    for (int off = 32; off > 0; off >>= 1) {
        norm_part += __shfl_xor(norm_part, off);
        amp_part  += __shfl_xor(amp_part,  off);
    }
    if (lane == 0) { redN[w] = norm_part; redA[w] = amp_part; }
    __syncthreads();
    if (t == 0) {
        float n = 0.f, a = 0.f;
        #pragma unroll
        for (int i = 0; i < 8; ++i) { n += redN[i]; a += redA[i]; }
        wnorm[b * 2 + h] = n;
        if (h == 0) wamp[b] = a;
    }
}

// Kernel 2: single block, 512 threads.
// mean(-log(amp^2/norm + eps)) + 0.01*(reg_c + reg_theta_m + reg_theta_p)
__global__ __launch_bounds__(512) void finalize_kernel(
    const float* __restrict__ wnorm, const float* __restrict__ wamp,
    const float* __restrict__ theta, const float* __restrict__ coef,
    float* __restrict__ out)
{
    const int t    = threadIdx.x;
    const int lane = t & 63;
    const int w    = t >> 6;
    __shared__ float r5[5][8];

    // per-b neg-logs (t < 128); 2 norm partials as one float2
    float mnl = 0.f;
    if (t < NB) {
        float a  = wamp[t];
        float2 n2 = reinterpret_cast<const float2*>(wnorm)[t];
        float n  = n2.x + n2.y;
        mnl = -__logf(a * a / n + 1e-20f);
    }
    float cv = (t < NMP) ? coef[t] : 0.f;

    // reg_theta_m: 64 (l,p) items, var over M, ddof=1
    float vm = 0.f;
    if (t < NL * NP) {
        int l = t >> 2, p = t & 3;
        float sum = 0.f, sum2 = 0.f;
        for (int m = 0; m < NM; ++m) {
            float x = theta[(l * NM + m) * NP + p];
            sum += x; sum2 += x * x;
        }
        vm = (sum2 - sum * sum / (float)NM) / (float)(NM - 1);
    }

    // reg_theta_p: 512 (l,m) items, exactly one float4 per thread
    float4 th = reinterpret_cast<const float4*>(theta)[t];
    float sum  = th.x + th.y + th.z + th.w;
    float sum2 = th.x * th.x + th.y * th.y + th.z * th.z + th.w * th.w;
    float vp = (sum2 - sum * sum * 0.25f) * (1.f / 3.f);

    float v1 = mnl, v2 = cv, v3 = cv * cv, v4 = vm, v5 = vp;
    #pragma unroll
    for (int off = 32; off > 0; off >>= 1) {
        v1 += __shfl_xor(v1, off);
        v2 += __shfl_xor(v2, off);
        v3 += __shfl_xor(v3, off);
        v4 += __shfl_xor(v4, off);
        v5 += __shfl_xor(v5, off);
    }
    if (lane == 0) {
        r5[0][w] = v1; r5[1][w] = v2; r5[2][w] = v3; r5[3][w] = v4; r5[4][w] = v5;
    }
    __syncthreads();
    if (t == 0) {
        float s1 = 0.f, s2 = 0.f, s3 = 0.f, s4 = 0.f, s5 = 0.f;
        #pragma unroll
        for (int i = 0; i < 8; ++i) {
            s1 += r5[0][i]; s2 += r5[1][i]; s3 += r5[2][i];
            s4 += r5[3][i]; s5 += r5[4][i];
        }
        float s_mnl  = s1 / (float)NB;
        float reg_c  = (s3 - s2 * s2 / (float)NMP) / (float)(NMP - 1);
        float reg_tm = s4 / (float)(NL * NP);
        float reg_tp = s5 / (float)(NL * NM);
        out[0] = s_mnl + 0.01f * (reg_c + reg_tm + reg_tp);
    }
}

extern "C" void kernel_launch(void* const* d_in, const int* in_sizes, int n_in,
                              void* d_out, int out_size, void* d_ws, size_t ws_size,
                              hipStream_t stream) {
    const float* ds    = (const float*)d_in[0];  // (B, L)
    const float* theta = (const float*)d_in[1];  // (L, M, P)
    const float* coef  = (const float*)d_in[2];  // (M, P)
    float* wnorm = (float*)d_ws;                 // 256 floats
    float* wamp  = (float*)d_ws + 2 * NB;        // 128 floats
    float* out   = (float*)d_out;

    per_b_kernel<<<2 * NB, 512, 0, stream>>>(ds, theta, coef, wnorm, wamp);
    finalize_kernel<<<1, 512, 0, stream>>>(wnorm, wamp, theta, coef, out);
}